// Round 6
// baseline (415.581 us; speedup 1.0000x reference)
//
#include <hip/hip_runtime.h>
#include <hip/hip_fp16.h>
#include <math.h>

#define KF 8
#define LL 8
#define TT (1 << 18)
#define FF 2
#define HID 64
#define INF 16          // L*F = MLP input dim
// LDS strides (floats), chosen so the 8 per-lane 'assign' values map to
// distinct/2-way bank groups for float4 reads:
//   W1: stride 1056 -> (1056/4)%32 = 8 bank-group step per cluster
#define W1S 1056
#define BS  68          // b1 / W2 per-cluster stride (68%32=4 offset; 2-way max)

#define NENT (KF * LL * TT)   // 16,777,216 table entries

// ---------------------------------------------------------------------------
// Round-6: round-5 established the fp16-table win (main kernel 273->210us,
// FETCH 765->580MB) but the repack helper itself cost ~200us (1.3 TB/s —
// latency-exposed scalar-ish streaming). Main kernel is FROZEN byte-for-byte;
// only the repack is rewritten for throughput: 8 entries/thread =
// 4x global_load_dwordx4 + 2x global_store_dwordx4, one-shot grid (8192
// blocks), 4 independent loads in flight per thread. Target ~40us.
// ---------------------------------------------------------------------------

__global__ __launch_bounds__(256) void repack_tables_fp16(
    const float4* __restrict__ src, uint4* __restrict__ dst, int nthreads)
{
    const int gid = blockIdx.x * blockDim.x + threadIdx.x;
    if (gid >= nthreads) return;
    const size_t b = (size_t)gid * 4;            // float4 index (2 entries each)

    const float4 f0 = src[b + 0];
    const float4 f1 = src[b + 1];
    const float4 f2 = src[b + 2];
    const float4 f3 = src[b + 3];

    uint4 d0, d1;
    {
        __half2 h;
        h = __floats2half2_rn(f0.x, f0.y); d0.x = *reinterpret_cast<unsigned*>(&h);
        h = __floats2half2_rn(f0.z, f0.w); d0.y = *reinterpret_cast<unsigned*>(&h);
        h = __floats2half2_rn(f1.x, f1.y); d0.z = *reinterpret_cast<unsigned*>(&h);
        h = __floats2half2_rn(f1.z, f1.w); d0.w = *reinterpret_cast<unsigned*>(&h);
        h = __floats2half2_rn(f2.x, f2.y); d1.x = *reinterpret_cast<unsigned*>(&h);
        h = __floats2half2_rn(f2.z, f2.w); d1.y = *reinterpret_cast<unsigned*>(&h);
        h = __floats2half2_rn(f3.x, f3.y); d1.z = *reinterpret_cast<unsigned*>(&h);
        h = __floats2half2_rn(f3.z, f3.w); d1.w = *reinterpret_cast<unsigned*>(&h);
    }
    dst[(size_t)gid * 2 + 0] = d0;
    dst[(size_t)gid * 2 + 1] = d1;
}

// Main kernel: EXACT round-5 structure (sW1 in LDS, 64-bit level pointers,
// 8 gathers in flight, no min-wave clamp), gathers are half2. FROZEN.
__global__ __launch_bounds__(256) void propnet_density_kernel_h(
    const float* __restrict__ positions,
    const float* __restrict__ centroids,
    const __half2* __restrict__ tables,
    const float* __restrict__ W1,
    const float* __restrict__ b1,
    const float* __restrict__ W2,
    const float* __restrict__ b2,
    float* __restrict__ out,
    int npts)
{
    __shared__ float sW1[KF * W1S];   // 33792 B
    __shared__ float sB1[KF * BS];    //  2176 B
    __shared__ float sW2[KF * BS];    //  2176 B
    __shared__ float sB2[KF];
    __shared__ float sC[KF * 3];

    const int tid = threadIdx.x;

    for (int idx = tid; idx < KF * INF * HID; idx += blockDim.x) {
        int k = idx >> 10;            // / (16*64)
        int r = idx & 1023;
        sW1[k * W1S + r] = W1[idx];
    }
    for (int idx = tid; idx < KF * HID; idx += blockDim.x) {
        int k = idx >> 6;
        int r = idx & 63;
        sB1[k * BS + r] = b1[idx];
        sW2[k * BS + r] = W2[idx];
    }
    if (tid < KF) sB2[tid] = b2[tid];
    if (tid < KF * 3) sC[tid] = centroids[tid];
    __syncthreads();

    const int gid = blockIdx.x * blockDim.x + tid;
    if (gid >= npts) return;

    const float px = positions[gid * 3 + 0];
    const float py = positions[gid * 3 + 1];
    const float pz = positions[gid * 3 + 2];

    // ---- cluster assignment: argmin_k ||p - c_k||^2 (first-min tie-break) ----
    int assign = 0;
    float best = 1e30f;
    #pragma unroll
    for (int k = 0; k < KF; ++k) {
        float dx = px - sC[k * 3 + 0];
        float dy = py - sC[k * 3 + 1];
        float dz = pz - sC[k * 3 + 2];
        float d2 = fmaf(dx, dx, fmaf(dy, dy, dz * dz));
        bool lt = d2 < best;
        assign = lt ? k : assign;
        best = lt ? d2 : best;
    }

    // ---- multiresolution hash encoding (half2 gathers) ----
    float enc[INF];
    const __half2* __restrict__ tab =
        tables + (size_t)assign * (LL * (size_t)TT);

    #pragma unroll
    for (int l = 0; l < LL; ++l) {
        const float res = (float)(16 << l);
        const float sx = px * res, sy = py * res, sz = pz * res;
        const float fx = floorf(sx), fy = floorf(sy), fz = floorf(sz);
        const float wx = sx - fx, wy = sy - fy, wz = sz - fz;
        const unsigned ix = (unsigned)(int)fx;
        const unsigned iy = (unsigned)(int)fy;
        const unsigned iz = (unsigned)(int)fz;

        const __half2* __restrict__ tl = tab + (size_t)l * TT;

        const unsigned hx0 = ix;                         // prime 1
        const unsigned hx1 = ix + 1u;
        const unsigned hy0 = iy * 2654435761u;
        const unsigned hy1 = (iy + 1u) * 2654435761u;
        const unsigned hz0 = iz * 805459861u;
        const unsigned hz1 = (iz + 1u) * 805459861u;
        const unsigned M = TT - 1;

        // 8 independent 4B gathers — keep them all in flight
        const __half2 c000 = tl[(hx0 ^ hy0 ^ hz0) & M];
        const __half2 c001 = tl[(hx0 ^ hy0 ^ hz1) & M];
        const __half2 c010 = tl[(hx0 ^ hy1 ^ hz0) & M];
        const __half2 c011 = tl[(hx0 ^ hy1 ^ hz1) & M];
        const __half2 c100 = tl[(hx1 ^ hy0 ^ hz0) & M];
        const __half2 c101 = tl[(hx1 ^ hy0 ^ hz1) & M];
        const __half2 c110 = tl[(hx1 ^ hy1 ^ hz0) & M];
        const __half2 c111 = tl[(hx1 ^ hy1 ^ hz1) & M];

        const float ux = 1.f - wx, uy = 1.f - wy, uz = 1.f - wz;
        const float w000 = ux * uy * uz, w001 = ux * uy * wz;
        const float w010 = ux * wy * uz, w011 = ux * wy * wz;
        const float w100 = wx * uy * uz, w101 = wx * uy * wz;
        const float w110 = wx * wy * uz, w111 = wx * wy * wz;

        enc[l * 2 + 0] = __low2float(c000) * w000 + __low2float(c001) * w001
                       + __low2float(c010) * w010 + __low2float(c011) * w011
                       + __low2float(c100) * w100 + __low2float(c101) * w101
                       + __low2float(c110) * w110 + __low2float(c111) * w111;
        enc[l * 2 + 1] = __high2float(c000) * w000 + __high2float(c001) * w001
                       + __high2float(c010) * w010 + __high2float(c011) * w011
                       + __high2float(c100) * w100 + __high2float(c101) * w101
                       + __high2float(c110) * w110 + __high2float(c111) * w111;
    }

    // ---- per-cluster MLP: out = b2 + sum_j relu(b1[j] + enc·W1[:,j]) * W2[j] ----
    const float4* __restrict__ w1k = (const float4*)(sW1 + assign * W1S);
    const float4* __restrict__ b1k = (const float4*)(sB1 + assign * BS);
    const float4* __restrict__ w2k = (const float4*)(sW2 + assign * BS);

    float outv = sB2[assign];
    #pragma unroll
    for (int j4 = 0; j4 < HID / 4; ++j4) {
        float4 a = b1k[j4];
        #pragma unroll
        for (int i = 0; i < INF; ++i) {
            const float4 w = w1k[i * (HID / 4) + j4];   // ds_read_b128
            const float e = enc[i];
            a.x = fmaf(e, w.x, a.x);
            a.y = fmaf(e, w.y, a.y);
            a.z = fmaf(e, w.z, a.z);
            a.w = fmaf(e, w.w, a.w);
        }
        a.x = fmaxf(a.x, 0.f); a.y = fmaxf(a.y, 0.f);
        a.z = fmaxf(a.z, 0.f); a.w = fmaxf(a.w, 0.f);
        const float4 w2v = w2k[j4];
        outv = fmaf(a.x, w2v.x, outv);
        outv = fmaf(a.y, w2v.y, outv);
        outv = fmaf(a.z, w2v.z, outv);
        outv = fmaf(a.w, w2v.w, outv);
    }

    out[gid] = expf(outv);
}

// Fallback (workspace too small): exact round-0 fp32 kernel.
__global__ __launch_bounds__(256) void propnet_density_kernel_f(
    const float* __restrict__ positions,
    const float* __restrict__ centroids,
    const float* __restrict__ tables,
    const float* __restrict__ W1,
    const float* __restrict__ b1,
    const float* __restrict__ W2,
    const float* __restrict__ b2,
    float* __restrict__ out,
    int npts)
{
    __shared__ float sW1[KF * W1S];
    __shared__ float sB1[KF * BS];
    __shared__ float sW2[KF * BS];
    __shared__ float sB2[KF];
    __shared__ float sC[KF * 3];

    const int tid = threadIdx.x;

    for (int idx = tid; idx < KF * INF * HID; idx += blockDim.x) {
        int k = idx >> 10;
        int r = idx & 1023;
        sW1[k * W1S + r] = W1[idx];
    }
    for (int idx = tid; idx < KF * HID; idx += blockDim.x) {
        int k = idx >> 6;
        int r = idx & 63;
        sB1[k * BS + r] = b1[idx];
        sW2[k * BS + r] = W2[idx];
    }
    if (tid < KF) sB2[tid] = b2[tid];
    if (tid < KF * 3) sC[tid] = centroids[tid];
    __syncthreads();

    const int gid = blockIdx.x * blockDim.x + tid;
    if (gid >= npts) return;

    const float px = positions[gid * 3 + 0];
    const float py = positions[gid * 3 + 1];
    const float pz = positions[gid * 3 + 2];

    int assign = 0;
    float best = 1e30f;
    #pragma unroll
    for (int k = 0; k < KF; ++k) {
        float dx = px - sC[k * 3 + 0];
        float dy = py - sC[k * 3 + 1];
        float dz = pz - sC[k * 3 + 2];
        float d2 = fmaf(dx, dx, fmaf(dy, dy, dz * dz));
        bool lt = d2 < best;
        assign = lt ? k : assign;
        best = lt ? d2 : best;
    }

    float enc[INF];
    const float2* __restrict__ tab =
        (const float2*)tables + (size_t)assign * (LL * (size_t)TT);

    #pragma unroll
    for (int l = 0; l < LL; ++l) {
        const float res = (float)(16 << l);
        const float sx = px * res, sy = py * res, sz = pz * res;
        const float fx = floorf(sx), fy = floorf(sy), fz = floorf(sz);
        const float wx = sx - fx, wy = sy - fy, wz = sz - fz;
        const unsigned ix = (unsigned)(int)fx;
        const unsigned iy = (unsigned)(int)fy;
        const unsigned iz = (unsigned)(int)fz;

        const float2* __restrict__ tl = tab + (size_t)l * TT;

        const unsigned hx0 = ix;
        const unsigned hx1 = ix + 1u;
        const unsigned hy0 = iy * 2654435761u;
        const unsigned hy1 = (iy + 1u) * 2654435761u;
        const unsigned hz0 = iz * 805459861u;
        const unsigned hz1 = (iz + 1u) * 805459861u;
        const unsigned M = TT - 1;

        const float2 c000 = tl[(hx0 ^ hy0 ^ hz0) & M];
        const float2 c001 = tl[(hx0 ^ hy0 ^ hz1) & M];
        const float2 c010 = tl[(hx0 ^ hy1 ^ hz0) & M];
        const float2 c011 = tl[(hx0 ^ hy1 ^ hz1) & M];
        const float2 c100 = tl[(hx1 ^ hy0 ^ hz0) & M];
        const float2 c101 = tl[(hx1 ^ hy0 ^ hz1) & M];
        const float2 c110 = tl[(hx1 ^ hy1 ^ hz0) & M];
        const float2 c111 = tl[(hx1 ^ hy1 ^ hz1) & M];

        const float ux = 1.f - wx, uy = 1.f - wy, uz = 1.f - wz;
        const float w000 = ux * uy * uz, w001 = ux * uy * wz;
        const float w010 = ux * wy * uz, w011 = ux * wy * wz;
        const float w100 = wx * uy * uz, w101 = wx * uy * wz;
        const float w110 = wx * wy * uz, w111 = wx * wy * wz;

        enc[l * 2 + 0] = c000.x * w000 + c001.x * w001 + c010.x * w010 + c011.x * w011
                       + c100.x * w100 + c101.x * w101 + c110.x * w110 + c111.x * w111;
        enc[l * 2 + 1] = c000.y * w000 + c001.y * w001 + c010.y * w010 + c011.y * w011
                       + c100.y * w100 + c101.y * w101 + c110.y * w110 + c111.y * w111;
    }

    const float4* __restrict__ w1k = (const float4*)(sW1 + assign * W1S);
    const float4* __restrict__ b1k = (const float4*)(sB1 + assign * BS);
    const float4* __restrict__ w2k = (const float4*)(sW2 + assign * BS);

    float outv = sB2[assign];
    #pragma unroll
    for (int j4 = 0; j4 < HID / 4; ++j4) {
        float4 a = b1k[j4];
        #pragma unroll
        for (int i = 0; i < INF; ++i) {
            const float4 w = w1k[i * (HID / 4) + j4];
            const float e = enc[i];
            a.x = fmaf(e, w.x, a.x);
            a.y = fmaf(e, w.y, a.y);
            a.z = fmaf(e, w.z, a.z);
            a.w = fmaf(e, w.w, a.w);
        }
        a.x = fmaxf(a.x, 0.f); a.y = fmaxf(a.y, 0.f);
        a.z = fmaxf(a.z, 0.f); a.w = fmaxf(a.w, 0.f);
        const float4 w2v = w2k[j4];
        outv = fmaf(a.x, w2v.x, outv);
        outv = fmaf(a.y, w2v.y, outv);
        outv = fmaf(a.z, w2v.z, outv);
        outv = fmaf(a.w, w2v.w, outv);
    }

    out[gid] = expf(outv);
}

extern "C" void kernel_launch(void* const* d_in, const int* in_sizes, int n_in,
                              void* d_out, int out_size, void* d_ws, size_t ws_size,
                              hipStream_t stream) {
    const float* positions = (const float*)d_in[0];
    const float* centroids = (const float*)d_in[1];
    const float* tables    = (const float*)d_in[2];
    const float* W1        = (const float*)d_in[3];
    const float* b1        = (const float*)d_in[4];
    const float* W2        = (const float*)d_in[5];
    const float* b2        = (const float*)d_in[6];
    float* out = (float*)d_out;

    const int npts = in_sizes[0] / 3;
    const int block = 256;
    const int grid = (npts + block - 1) / block;

    const size_t needed = (size_t)NENT * sizeof(__half2);   // 64 MiB
    if (ws_size >= needed && d_ws != nullptr) {
        // repack tables fp32 -> half2, 8 entries/thread, one-shot grid
        // (re-run every launch: inputs may be re-poisoned between iterations)
        const int nthreads = NENT / 8;                       // 2,097,152
        const int rgrid = nthreads / 256;                    // 8192 blocks
        repack_tables_fp16<<<rgrid, 256, 0, stream>>>(
            (const float4*)tables, (uint4*)d_ws, nthreads);
        propnet_density_kernel_h<<<grid, block, 0, stream>>>(
            positions, centroids, (const __half2*)d_ws, W1, b1, W2, b2, out, npts);
    } else {
        propnet_density_kernel_f<<<grid, block, 0, stream>>>(
            positions, centroids, tables, W1, b1, W2, b2, out, npts);
    }
}